// Round 9
// baseline (282.952 us; speedup 1.0000x reference)
//
#include <hip/hip_runtime.h>
#include <hip/hip_bf16.h>

#define NTOK 49
#define CDIM 128
#define SCALE 0.17677669529663687f
#define LOG2E 1.4426950408889634f

// packed table sizes (elements)
#define CMB_ELEMS (64*4*4*16*4*16)    // 1048576 f32 [w][h][ct][ln][quad][rt][r] = (mask+rpb)*LOG2E
#define PWQK_ELEMS  (4*4*4*4*16*8)    // 32768 bf16  [h][rt][ks][quad][ln][j]  (A-frags of Wq/Wk^T)
#define PV_ELEMS    (8*4*4*16*8)      // 16384 bf16  [c2][ks][quad][ln][j]     (B-frags of Wv)
#define PWP_ELEMS   (8*4*4*16*8)      // 16384 bf16  [rt][ks][quad][ln][j]     (A-frags of Wproj^T)

// Per-head region HSZ = 4608 shorts (r6/r8 geometry, measured 0 bank conflicts):
//   q[n][QS=36] @0 ; k @KOFFS ; P[n][PS=68] aliases q+k ; v^T[32][VS=68] after P reads ;
//   O[n][OS=36] overwrites q/P region after reads.  Strides 18/34 dwords -> balanced banks.
//
// r9 STRUCTURE CHANGE: block = 2 windows (grid 2048), wave h = head h of BOTH windows,
// two chains interleaved per wave:
//   xA -> A_A(qkv) -> [issue xB half1] B_A(QK+softmax) [pack xB.1, issue xB half2]
//   -> C_A(PV) [pack xB.2] -> A_B(qkv) -> bar1 -> D_A(proj) -> B_B -> C_B -> bar2 -> D_B
// Rationale: r1->r4 showed +50% waves ~ null (waves stall lockstep on same phase); only
// WITHIN-wave ILP ever paid.  This hides window-B's x HBM latency (the largest single
// unhidden stall) under window-A compute and doubles independent chains per SIMD.
// LDS 2*18432 shorts = 73728 B -> 2 blocks/CU -> 2 waves/SIMD -> 256-reg budget
// (launch_bounds(256,2)); peak liveness ~200 regs by construction (x staged in half-batches).
// Grid 2048 = exactly 4 generations at 512 block-slots (no ragged tail).
//
// History: r1 144 | r2 185 (spill cliff at 128-reg cap) | r3 158 | r4 141 | r5 prep null
//   r6 140 | r7 148.5 (b128 bank conflicts) | r8 139 (exp2+late-norm+setprio, conflicts 0)
#define QS 36
#define PS 68
#define VS 68
#define OS 36
#define KOFFS (64*QS)          // 2304
#define HSZ   (2*KOFFS)        // 4608
#define WSZ   (4*HSZ)          // per-window region: 18432 shorts
#define LDS_SH (2*WSZ)         // 36864 shorts = 73728 B = 144*512 -> 2 blocks/CU

typedef __attribute__((ext_vector_type(8))) __bf16 bf16x8;
typedef __attribute__((ext_vector_type(4))) float f32x4;

__device__ __forceinline__ unsigned short f2bf(float f) {
  unsigned int u = __float_as_uint(f);
  u += 0x7fffu + ((u >> 16) & 1u);   // RTNE
  return (unsigned short)(u >> 16);
}

__device__ __forceinline__ unsigned int pk2(float a, float b) {
  union { __hip_bfloat162 h2; unsigned int u; } r;
  r.h2 = __float22bfloat162_rn(make_float2(a, b));
  return r.u;
}
__device__ __forceinline__ unsigned long long pk4(float a, float b, float c, float d) {
  return (unsigned long long)pk2(a, b) | ((unsigned long long)pk2(c, d) << 32);
}
__device__ __forceinline__ bf16x8 pack8(float4 a, float4 b) {
  union { bf16x8 v; unsigned int u[4]; } r;
  r.u[0] = pk2(a.x, a.y); r.u[1] = pk2(a.z, a.w);
  r.u[2] = pk2(b.x, b.y); r.u[3] = pk2(b.z, b.w);
  return r.v;
}
// two ds_read_b64 (rows 8B- but not 16B-aligned; conflict-free on 18/34-dword strides)
__device__ __forceinline__ bf16x8 ld8(const unsigned short* p) {
  union { bf16x8 v; unsigned long long q[2]; } r;
  r.q[0] = *(const unsigned long long*)(p);
  r.q[1] = *(const unsigned long long*)(p + 4);
  return r.v;
}

// ---- prep: LDS-staged cmb build (blocks 0..255) + weight fragments (blocks 256..511) ----
__global__ __launch_bounds__(256) void prep_kernel(
    const float* __restrict__ mask,
    const float* __restrict__ qkv_w,
    const float* __restrict__ proj_w,
    const float* __restrict__ bias_table,
    const int* __restrict__ rel_index,
    float* __restrict__ cmb,
    unsigned short* __restrict__ pwqk,
    unsigned short* __restrict__ pv,
    unsigned short* __restrict__ pwp) {
  const int t = threadIdx.x;
  if (blockIdx.x < 256) {
    __shared__ float sm[NTOK * NTOK];
    __shared__ int   sri[NTOK * NTOK];
    __shared__ float sbt[169 * 4];
    const int w = blockIdx.x >> 2;
    const int h = blockIdx.x & 3;
    const float* mw = mask + (size_t)w * (NTOK * NTOK);
    for (int i = t; i < NTOK * NTOK; i += 256) { sm[i] = mw[i]; sri[i] = rel_index[i]; }
    for (int i = t; i < 169 * 4; i += 256) sbt[i] = bias_table[i];
    __syncthreads();
    float* cw = cmb + ((size_t)w * 4 + h) * 4096;
    #pragma unroll
    for (int o0 = 0; o0 < 4096; o0 += 256) {
      const int o = o0 + t;
      const int r = o & 3, rt = (o >> 2) & 3, quad = (o >> 4) & 3,
                ln = (o >> 6) & 15, ct = (o >> 10) & 3;
      const int n = ct * 16 + ln;
      const int m = rt * 16 + quad * 4 + r;
      float v;
      if (m >= NTOK)      v = -1e30f;   // masked rows: exp2 -> 0
      else if (n >= NTOK) v = 0.0f;     // pad cols: outputs discarded later
      else {
        const int idx = n * NTOK + m;
        v = (sm[idx] + sbt[sri[idx] * 4 + h]) * LOG2E;   // pre-scale for exp2
      }
      cw[o] = v;
    }
    return;
  }
  int i = (blockIdx.x - 256) * 256 + t;
  if (i < PWQK_ELEMS) {
    int j = i & 7, ln = (i >> 3) & 15, quad = (i >> 7) & 3, ks = (i >> 9) & 3,
        rt = (i >> 11) & 3, h = (i >> 13) & 3;
    int kk  = ks * 32 + quad * 8 + j;
    int col = (rt < 2) ? (h * 32 + rt * 16 + ln) : (128 + h * 32 + (rt - 2) * 16 + ln);
    pwqk[i] = f2bf(qkv_w[kk * 384 + col]);
    return;
  }
  i -= PWQK_ELEMS;
  if (i < PV_ELEMS) {
    int j = i & 7, ln = (i >> 3) & 15, quad = (i >> 7) & 3, ks = (i >> 9) & 3, c2 = (i >> 11) & 7;
    pv[i] = f2bf(qkv_w[(ks * 32 + quad * 8 + j) * 384 + 256 + c2 * 16 + ln]);
    return;
  }
  i -= PV_ELEMS;
  if (i < PWP_ELEMS) {
    int j = i & 7, ln = (i >> 3) & 15, quad = (i >> 7) & 3, ks = (i >> 9) & 3, rt = (i >> 11) & 7;
    pwp[i] = f2bf(proj_w[(ks * 32 + quad * 8 + j) * 128 + rt * 16 + ln]);
  }
}

// ================= per-stage helpers (bodies byte-equivalent to r8) =================

__device__ __forceinline__ void x_issue_half(const float* __restrict__ xb, int half,
                                             int ln, int quad, float4 xr[16]) {
  #pragma unroll
  for (int rt = 0; rt < 4; rt++) {
    const int row = rt * 16 + ln;
    #pragma unroll
    for (int k2 = 0; k2 < 2; k2++) {
      const int idx = (rt * 2 + k2) * 2;
      if (row < NTOK) {
        const float* p = xb + row * CDIM + (half * 2 + k2) * 32 + quad * 8;
        xr[idx]     = *(const float4*)p;
        xr[idx + 1] = *(const float4*)(p + 4);
      } else {
        float4 z = {0.f, 0.f, 0.f, 0.f};
        xr[idx] = z; xr[idx + 1] = z;
      }
    }
  }
}
__device__ __forceinline__ void x_pack_half(const float4 xr[16], int half, bf16x8 afr[4][4]) {
  #pragma unroll
  for (int rt = 0; rt < 4; rt++)
    #pragma unroll
    for (int k2 = 0; k2 < 2; k2++)
      afr[rt][half * 2 + k2] = pack8(xr[(rt * 2 + k2) * 2], xr[(rt * 2 + k2) * 2 + 1]);
}

// v = x @ Wv ; v^T packed quadruples kept in regs
__device__ __forceinline__ void stage_av(const bf16x8 afr[4][4],
                                         const unsigned short* __restrict__ pv,
                                         const float* __restrict__ qkv_b,
                                         int h, int ln, int quad,
                                         unsigned long long hv[2][4]) {
  #pragma unroll
  for (int ci = 0; ci < 2; ci++) {
    bf16x8 bvf[4];
    #pragma unroll
    for (int ks = 0; ks < 4; ks++)
      bvf[ks] = *(const bf16x8*)&pv[((((h*2 + ci)*4 + ks)*4 + quad)*16 + ln)*8];
    const float bvb = qkv_b[256 + (h*2 + ci)*16 + ln];
    f32x4 acc[4];
    #pragma unroll
    for (int rt = 0; rt < 4; rt++) { f32x4 bi = {bvb, bvb, bvb, bvb}; acc[rt] = bi; }
    __builtin_amdgcn_s_setprio(1);
    #pragma unroll
    for (int ks = 0; ks < 4; ks++)
      #pragma unroll
      for (int rt = 0; rt < 4; rt++)
        acc[rt] = __builtin_amdgcn_mfma_f32_16x16x32_bf16(afr[rt][ks], bvf[ks], acc[rt], 0, 0, 0);
    __builtin_amdgcn_s_setprio(0);
    #pragma unroll
    for (int rt = 0; rt < 4; rt++)
      hv[ci][rt] = pk4(acc[rt][0], acc[rt][1], acc[rt][2], acc[rt][3]);
  }
}

// qkv^T = W^T @ x^T ; q (scaled, log2e-folded) and k written to LDS
__device__ __forceinline__ void stage_aqk(const bf16x8 afr[4][4],
                                          const unsigned short* __restrict__ pwqk,
                                          const float* __restrict__ qkv_b,
                                          int h, int ln, int quad,
                                          unsigned short* hb) {
  #pragma unroll
  for (int rt = 0; rt < 4; rt++) {
    bf16x8 awf[4];
    #pragma unroll
    for (int ks = 0; ks < 4; ks++)
      awf[ks] = *(const bf16x8*)&pwqk[((((h*4 + rt)*4 + ks)*4 + quad)*16 + ln)*8];
    const int fb = (rt < 2) ? (h*32 + rt*16 + quad*4) : (128 + h*32 + (rt - 2)*16 + quad*4);
    const float4 qb4 = *(const float4*)&qkv_b[fb];
    f32x4 acc2[4];
    #pragma unroll
    for (int ct = 0; ct < 4; ct++) { f32x4 bi = {qb4.x, qb4.y, qb4.z, qb4.w}; acc2[ct] = bi; }
    __builtin_amdgcn_s_setprio(1);
    #pragma unroll
    for (int ks = 0; ks < 4; ks++)
      #pragma unroll
      for (int ct = 0; ct < 4; ct++)
        acc2[ct] = __builtin_amdgcn_mfma_f32_16x16x32_bf16(awf[ks], afr[ct][ks], acc2[ct], 0, 0, 0);
    __builtin_amdgcn_s_setprio(0);
    const int base = (rt < 2) ? 0 : KOFFS;
    const int d0   = (rt < 2) ? (rt*16 + quad*4) : ((rt - 2)*16 + quad*4);
    const float sc = (rt < 2) ? (SCALE * LOG2E) : 1.0f;
    #pragma unroll
    for (int ct = 0; ct < 4; ct++)
      *(unsigned long long*)&hb[base + (ct*16 + ln)*QS + d0] =
          pk4(acc2[ct][0]*sc, acc2[ct][1]*sc, acc2[ct][2]*sc, acc2[ct][3]*sc);
  }
}

// S^T = k·q^T (acc-init from cmb), exp2, row-sums; raw e written to P; inv returned
__device__ __forceinline__ void stage_b(unsigned short* hb, const float* __restrict__ cw,
                                        int ln, int quad, float inv[4]) {
  f32x4 sacc[4][4];
  #pragma unroll
  for (int ct = 0; ct < 4; ct++)
    #pragma unroll
    for (int rt = 0; rt < 4; rt++)
      sacc[ct][rt] = *(const f32x4*)(cw + ct*1024 + rt*4);

  bf16x8 ka[4], qb2[4];
  #pragma unroll
  for (int rt = 0; rt < 4; rt++) ka[rt]  = ld8(&hb[KOFFS + (rt*16 + ln)*QS + quad*8]);
  #pragma unroll
  for (int ct = 0; ct < 4; ct++) qb2[ct] = ld8(&hb[(ct*16 + ln)*QS + quad*8]);

  __builtin_amdgcn_s_setprio(1);
  #pragma unroll
  for (int ct = 0; ct < 4; ct++)
    #pragma unroll
    for (int rt = 0; rt < 4; rt++)
      sacc[ct][rt] = __builtin_amdgcn_mfma_f32_16x16x32_bf16(ka[rt], qb2[ct], sacc[ct][rt], 0, 0, 0);
  __builtin_amdgcn_s_setprio(0);

  float s[4] = {0.f, 0.f, 0.f, 0.f};
  #pragma unroll
  for (int ct = 0; ct < 4; ct++)
    #pragma unroll
    for (int rt = 0; rt < 4; rt++)
      #pragma unroll
      for (int r = 0; r < 4; r++) {
        const float e = __builtin_amdgcn_exp2f(sacc[ct][rt][r]);   // m>=49 rows: -1e30 -> 0
        sacc[ct][rt][r] = e;
        s[ct] += e;
      }
  #pragma unroll
  for (int ct = 0; ct < 4; ct++) s[ct] += __shfl_xor(s[ct], 16, 64);
  #pragma unroll
  for (int ct = 0; ct < 4; ct++) s[ct] += __shfl_xor(s[ct], 32, 64);
  #pragma unroll
  for (int ct = 0; ct < 4; ct++) inv[ct] = 1.0f / s[ct];
  #pragma unroll
  for (int ct = 0; ct < 4; ct++)
    #pragma unroll
    for (int rt = 0; rt < 4; rt++)
      *(unsigned long long*)&hb[(ct*16 + ln)*PS + rt*16 + quad*4] =
          pk4(sacc[ct][rt][0], sacc[ct][rt][1], sacc[ct][rt][2], sacc[ct][rt][3]);
}

// O^T = v^T · E^T, scaled by inv at the write (late normalize); O into own head region
__device__ __forceinline__ void stage_c(unsigned short* hb, const unsigned long long hv[2][4],
                                        const float inv[4], int ln, int quad) {
  bf16x8 pb[4][2];
  #pragma unroll
  for (int ct = 0; ct < 4; ct++)
    #pragma unroll
    for (int ks = 0; ks < 2; ks++)
      pb[ct][ks] = ld8(&hb[(ct*16 + ln)*PS + ks*32 + quad*8]);
  #pragma unroll
  for (int ci = 0; ci < 2; ci++)
    #pragma unroll
    for (int rt = 0; rt < 4; rt++)
      *(unsigned long long*)&hb[(ci*16 + ln)*VS + rt*16 + quad*4] = hv[ci][rt];
  bf16x8 va[2][2];
  #pragma unroll
  for (int rt = 0; rt < 2; rt++)
    #pragma unroll
    for (int ks = 0; ks < 2; ks++)
      va[rt][ks] = ld8(&hb[(rt*16 + ln)*VS + ks*32 + quad*8]);
  f32x4 oacc[2][4];
  #pragma unroll
  for (int rt = 0; rt < 2; rt++)
    #pragma unroll
    for (int ct = 0; ct < 4; ct++) { f32x4 z = {0.f, 0.f, 0.f, 0.f}; oacc[rt][ct] = z; }
  __builtin_amdgcn_s_setprio(1);
  #pragma unroll
  for (int ks = 0; ks < 2; ks++)
    #pragma unroll
    for (int rt = 0; rt < 2; rt++)
      #pragma unroll
      for (int ct = 0; ct < 4; ct++)
        oacc[rt][ct] = __builtin_amdgcn_mfma_f32_16x16x32_bf16(va[rt][ks], pb[ct][ks], oacc[rt][ct], 0, 0, 0);
  __builtin_amdgcn_s_setprio(0);
  #pragma unroll
  for (int rt = 0; rt < 2; rt++)
    #pragma unroll
    for (int ct = 0; ct < 4; ct++) {
      const int n = ct*16 + ln;
      if (n < 56)
        *(unsigned long long*)&hb[n*OS + rt*16 + quad*4] =
            pk4(oacc[rt][ct][0]*inv[ct], oacc[rt][ct][1]*inv[ct],
                oacc[rt][ct][2]*inv[ct], oacc[rt][ct][3]*inv[ct]);
    }
}

// out^T = Wproj^T · O^T over the window's 4 head regions; float4 global stores
__device__ __forceinline__ void stage_d(const unsigned short* winBase,
                                        const bf16x8 wpa[2][4], const float4 pb4[2],
                                        float* __restrict__ obp, int h, int ln, int quad) {
  bf16x8 ob[4][4];
  #pragma unroll
  for (int ct = 0; ct < 4; ct++)
    #pragma unroll
    for (int ks = 0; ks < 4; ks++)
      ob[ct][ks] = ld8(&winBase[ks*HSZ + (ct*16 + ln)*OS + quad*8]);
  #pragma unroll
  for (int rt = 0; rt < 2; rt++) {
    const int c0 = (h*2 + rt)*16 + quad*4;
    f32x4 pacc[4];
    #pragma unroll
    for (int ct = 0; ct < 4; ct++) {
      f32x4 bi = {pb4[rt].x, pb4[rt].y, pb4[rt].z, pb4[rt].w};
      pacc[ct] = bi;
    }
    __builtin_amdgcn_s_setprio(1);
    #pragma unroll
    for (int ks = 0; ks < 4; ks++)
      #pragma unroll
      for (int ct = 0; ct < 4; ct++)
        pacc[ct] = __builtin_amdgcn_mfma_f32_16x16x32_bf16(wpa[rt][ks], ob[ct][ks], pacc[ct], 0, 0, 0);
    __builtin_amdgcn_s_setprio(0);
    #pragma unroll
    for (int ct = 0; ct < 4; ct++) {
      const int n = ct*16 + ln;
      if (n < NTOK) {
        float4 v4;
        v4.x = pacc[ct][0]; v4.y = pacc[ct][1]; v4.z = pacc[ct][2]; v4.w = pacc[ct][3];
        *(float4*)(obp + n*CDIM + c0) = v4;
      }
    }
  }
}

// ---- fused window attention: 1 block = 2 windows, wave h = head h of both (interleaved) ----
__global__ __launch_bounds__(256, 2) void win_attn_kernel(
    const float* __restrict__ x,
    const float* __restrict__ qkv_b,
    const float* __restrict__ proj_b,
    const float* __restrict__ cmb,
    const unsigned short* __restrict__ pwqk,
    const unsigned short* __restrict__ pv,
    const unsigned short* __restrict__ pwp,
    float* __restrict__ out)
{
  __shared__ alignas(16) unsigned short lds[LDS_SH];

  const int bid  = blockIdx.x;
  const int bA   = bid * 2;
  const int bB   = bid * 2 + 1;
  const int tid  = threadIdx.x;
  const int h    = tid >> 6;
  const int lane = tid & 63;
  const int ln   = lane & 15;
  const int quad = lane >> 4;

  unsigned short* hbA = lds + h * HSZ;
  unsigned short* hbB = lds + WSZ + h * HSZ;

  // ---- window A: load+pack x (block start; hidden only by other resident blocks) ----
  bf16x8 afrA[4][4];
  {
    const float* xbA = x + (size_t)bA * (NTOK * CDIM);
    float4 xr[16];
    x_issue_half(xbA, 0, ln, quad, xr);
    x_pack_half(xr, 0, afrA);
    x_issue_half(xbA, 1, ln, quad, xr);
    x_pack_half(xr, 1, afrA);
  }
  unsigned long long hvA[2][4];
  stage_av(afrA, pv, qkv_b, h, ln, quad, hvA);
  stage_aqk(afrA, pwqk, qkv_b, h, ln, quad, hbA);   // afrA dead after this

  // ---- issue window-B x loads (half 1) BEFORE B_A: HBM latency hides under QK+softmax ----
  const float* xbB = x + (size_t)bB * (NTOK * CDIM);
  bf16x8 afrB[4][4];
  float4 xr0[16];
  x_issue_half(xbB, 0, ln, quad, xr0);

  float invA[4];
  const float* cwA = cmb + (((size_t)(bA & 63) * 4 + h) * 4096) + (ln*4 + quad)*16;
  stage_b(hbA, cwA, ln, quad, invA);

  x_pack_half(xr0, 0, afrB);          // xr0 arrived during B_A
  float4 xr1[16];
  x_issue_half(xbB, 1, ln, quad, xr1); // half 2 hides under C_A

  stage_c(hbA, hvA, invA, ln, quad);

  x_pack_half(xr1, 1, afrB);

  unsigned long long hvB[2][4];
  stage_av(afrB, pv, qkv_b, h, ln, quad, hvB);
  stage_aqk(afrB, pwqk, qkv_b, h, ln, quad, hbB);

  // proj weights hoisted once for BOTH windows (L2 latency overlaps barrier wait)
  bf16x8 wpa[2][4];
  float4 pb4[2];
  #pragma unroll
  for (int rt = 0; rt < 2; rt++) {
    #pragma unroll
    for (int ks = 0; ks < 4; ks++)
      wpa[rt][ks] = *(const bf16x8*)&pwp[((((h*2 + rt)*4 + ks)*4 + quad)*16 + ln)*8];
    pb4[rt] = *(const float4*)&proj_b[(h*2 + rt)*16 + quad*4];
  }

  __syncthreads();   // bar1: all O_A slices complete

  stage_d(lds, wpa, pb4, out + (size_t)bA * (NTOK * CDIM), h, ln, quad);

  float invB[4];
  const float* cwB = cmb + (((size_t)(bB & 63) * 4 + h) * 4096) + (ln*4 + quad)*16;
  stage_b(hbB, cwB, ln, quad, invB);
  stage_c(hbB, hvB, invB, ln, quad);

  __syncthreads();   // bar2: all O_B slices complete

  stage_d(lds + WSZ, wpa, pb4, out + (size_t)bB * (NTOK * CDIM), h, ln, quad);
}

extern "C" void kernel_launch(void* const* d_in, const int* in_sizes, int n_in,
                              void* d_out, int out_size, void* d_ws, size_t ws_size,
                              hipStream_t stream) {
  const float* x          = (const float*)d_in[0];
  const float* mask       = (const float*)d_in[1];
  const float* qkv_w      = (const float*)d_in[2];
  const float* qkv_b      = (const float*)d_in[3];
  const float* proj_w     = (const float*)d_in[4];
  const float* proj_b     = (const float*)d_in[5];
  const float* bias_table = (const float*)d_in[6];
  const int*   rel_index  = (const int*)d_in[7];
  float* out = (float*)d_out;

  char* ws = (char*)d_ws;
  float* cmb            = (float*)ws;
  unsigned short* pwqk  = (unsigned short*)(ws + (size_t)CMB_ELEMS*4);
  unsigned short* pv    = (unsigned short*)(ws + (size_t)CMB_ELEMS*4 + (size_t)PWQK_ELEMS*2);
  unsigned short* pwp   = (unsigned short*)(ws + (size_t)CMB_ELEMS*4 + (size_t)(PWQK_ELEMS + PV_ELEMS)*2);

  // blocks 0..255: cmb (one per (w,h), LDS-staged); blocks 256..511: weight frags (1 elem/thread)
  prep_kernel<<<512, 256, 0, stream>>>(
      mask, qkv_w, proj_w, bias_table, rel_index, cmb, pwqk, pv, pwp);
  // 2 windows per block
  win_attn_kernel<<<2048, 256, 0, stream>>>(
      x, qkv_b, proj_b, cmb, pwqk, pv, pwp, out);
}